// Round 4
// baseline (411.357 us; speedup 1.0000x reference)
//
#include <hip/hip_runtime.h>

#define B_ 16
#define N_ 16384
#define C_ 128
#define H_ 512
#define W_ 512
#define L_ 65
#define FG 64

#define CHUNKS 32
#define PTS_PER_BLOCK (N_ / CHUNKS)      // 512
#define BLK 512                           // 8 waves/block, 2 blocks/CU

// ws layout (float units)
#define OFF_SUMS 0
#define OFF_CNT  (B_*L_*C_)              // 133120
#define OFF_DIST (OFF_CNT + B_*L_)       // 134160
#define OFF_LAB  (OFF_DIST + B_*L_)      // 135200 (ints from here, B_*N_)

__global__ __launch_bounds__(256) void k_zero(float* __restrict__ ws, float* __restrict__ out) {
    int i = blockIdx.x * 256 + threadIdx.x;
    if (i < OFF_LAB) ws[i] = 0.f;
    if (i == 0) out[0] = 0.f;
}

// one thread per point: gather label, save it, count it
__global__ __launch_bounds__(256) void k_labels(const int2* __restrict__ coords,
                                                const int* __restrict__ y,
                                                float* __restrict__ ws) {
    int t = blockIdx.x * 256 + threadIdx.x;           // 0 .. B*N-1
    int b = t >> 14;
    int2 rc = coords[t];
    int lab = y[(b << 18) + (rc.x << 9) + rc.y];
    ((int*)(ws + OFF_LAB))[t] = lab;
    unsafeAtomicAdd(ws + OFF_CNT + b * L_ + lab, 1.f);
}

// pass 1: segment-sum emb into per-image sums.  dwordx4 loads, swizzled ds_add.
__global__ __launch_bounds__(BLK) void k_accum(const float* __restrict__ emb,
                                               float* __restrict__ ws) {
    __shared__ float s_sum[L_ * C_];
    const int b = blockIdx.x / CHUNKS;
    const int chunk = blockIdx.x % CHUNKS;
    const int wave = threadIdx.x >> 6, lane = threadIdx.x & 63;
    const int half = lane >> 5, j = lane & 31, g = j >> 3;

    for (int i = threadIdx.x; i < L_ * C_; i += BLK) s_sum[i] = 0.f;
    __syncthreads();

    const int* labws = (const int*)(ws + OFF_LAB) + b * N_;
    const float* embb = emb + (size_t)b * N_ * C_;

    const int nbase = chunk * PTS_PER_BLOCK + wave * 64;
    int labv = labws[nbase + lane];                   // coalesced label read

    for (int i = 0; i < 32; ++i) {
        // lanes 0-31 -> point nbase+2i, lanes 32-63 -> point nbase+2i+1; 16B/lane
        float4 e = *(const float4*)(embb + (size_t)(nbase + 2 * i + half) * C_ + 4 * j);
        int lb = __shfl(labv, 2 * i + half);
        const float ev[4] = {e.x, e.y, e.z, e.w};
        #pragma unroll
        for (int k = 0; k < 4; ++k) {
            int slot = 4 * j + ((k + g) & 3);         // conflict-free swizzle
            unsafeAtomicAdd(&s_sum[lb * C_ + slot], ev[k]);
        }
    }
    __syncthreads();
    float* gs = ws + OFF_SUMS + b * L_ * C_;
    for (int idx = threadIdx.x; idx < L_ * C_; idx += BLK) {
        int row = idx >> 7, cc = idx & 127;
        int jj = cc >> 2, m = cc & 3, gg = jj >> 3;
        int truec = 4 * jj + ((m - gg) & 3);          // unswizzle
        unsafeAtomicAdd(&gs[(row << 7) + truec], s_sum[idx]);
    }
}

__global__ __launch_bounds__(256) void k_final_cent(float* __restrict__ ws) {
    int i = blockIdx.x * 256 + threadIdx.x;
    if (i >= B_ * L_ * C_) return;
    float cnt = ws[OFF_CNT + (i / C_)];
    ws[OFF_SUMS + i] = ws[OFF_SUMS + i] / fmaxf(cnt, 1.f);
}

// pass 2: per-point distance to own centroid, segment-summed
__global__ __launch_bounds__(BLK) void k_dist(const float* __restrict__ emb,
                                              float* __restrict__ ws) {
    __shared__ float s_cent[L_ * C_];   // swizzled storage
    __shared__ float s_dist[L_];
    const int b = blockIdx.x / CHUNKS;
    const int chunk = blockIdx.x % CHUNKS;
    const int wave = threadIdx.x >> 6, lane = threadIdx.x & 63;
    const int half = lane >> 5, j = lane & 31, g = j >> 3;

    const float* gcent = ws + OFF_SUMS + b * L_ * C_;
    for (int idx = threadIdx.x; idx < L_ * C_; idx += BLK) {
        int row = idx >> 7, cc = idx & 127;
        int jj = cc >> 2, m = cc & 3, gg = jj >> 3;
        int truec = 4 * jj + ((m - gg) & 3);
        s_cent[idx] = gcent[(row << 7) + truec];      // store swizzled
    }
    if (threadIdx.x < L_) s_dist[threadIdx.x] = 0.f;
    __syncthreads();

    const int* labws = (const int*)(ws + OFF_LAB) + b * N_;
    const float* embb = emb + (size_t)b * N_ * C_;

    const int nbase = chunk * PTS_PER_BLOCK + wave * 64;
    int labv = labws[nbase + lane];

    for (int i = 0; i < 32; ++i) {
        float4 e = *(const float4*)(embb + (size_t)(nbase + 2 * i + half) * C_ + 4 * j);
        int lb = __shfl(labv, 2 * i + half);
        const float ev[4] = {e.x, e.y, e.z, e.w};
        float ss = 0.f;
        #pragma unroll
        for (int k = 0; k < 4; ++k) {
            int slot = 4 * j + ((k + g) & 3);         // conflict-free ds_read_b32
            float d = ev[k] - s_cent[lb * C_ + slot];
            ss += d * d;
        }
        // reduce within each 32-lane half (both halves in parallel)
        ss += __shfl_xor(ss, 1);
        ss += __shfl_xor(ss, 2);
        ss += __shfl_xor(ss, 4);
        ss += __shfl_xor(ss, 8);
        ss += __shfl_xor(ss, 16);
        if (j == 0) unsafeAtomicAdd(&s_dist[lb], sqrtf(fmaxf(ss, 1e-12f)));
    }
    __syncthreads();
    float* gd = ws + OFF_DIST + b * L_;
    if (threadIdx.x < L_) unsafeAtomicAdd(&gd[threadIdx.x], s_dist[threadIdx.x]);
}

#define CSTRIDE 132  // 128 + 4 pad -> conflict-free float4 tile reads

__global__ __launch_bounds__(256) void k_final(float* __restrict__ ws, float* __restrict__ out) {
    __shared__ __align__(16) float s_cc[FG * CSTRIDE];
    __shared__ float s_present[FG];
    __shared__ float s_red[3];  // [0]=pull, [1]=push num, [2]=npairs
    const int b = blockIdx.x;
    const int t = threadIdx.x;

    const float* gcent = ws + OFF_SUMS + b * L_ * C_;
    for (int i = t; i < FG * C_; i += 256) {
        int l = i >> 7, ch = i & 127;
        s_cc[l * CSTRIDE + ch] = gcent[(l + 1) * C_ + ch];
    }
    if (t < 3) s_red[t] = 0.f;
    if (t < FG) {  // exactly wave 0
        float cnt = ws[OFF_CNT + b * L_ + 1 + t];
        s_present[t] = (cnt > 0.f) ? 1.f : 0.f;
        float pl = (cnt > 0.f) ? ws[OFF_DIST + b * L_ + 1 + t] / cnt : 0.f;
        #pragma unroll
        for (int off = 32; off; off >>= 1) pl += __shfl_xor(pl, off);
        if (t == 0) s_red[0] = pl;
    }
    __syncthreads();

    const int wave = t >> 6, lane = t & 63;
    const int ti = lane >> 3, tj = lane & 7;
    float psum = 0.f, pnp = 0.f;
    for (int tt = wave; tt < 36; tt += 4) {
        int a = 0, c = tt;
        while (c >= 8 - a) { c -= 8 - a; ++a; }
        c += a;  // tile (a, c), a <= c
        int i = a * 8 + ti, jx = c * 8 + tj;
        float acc = 0.f;
        #pragma unroll
        for (int ch = 0; ch < C_; ch += 4) {
            float4 xi = *(const float4*)&s_cc[i * CSTRIDE + ch];
            float4 xj = *(const float4*)&s_cc[jx * CSTRIDE + ch];
            float dx = xi.x - xj.x, dy = xi.y - xj.y;
            float dz = xi.z - xj.z, dw = xi.w - xj.w;
            acc += dx * dx + dy * dy + dz * dz + dw * dw;
        }
        float dm = sqrtf(fmaxf(acc, 1e-12f));
        float pv = fmaxf(1.f - dm, 0.f);           // PUSH_MARGIN = 1
        bool valid = (i < jx) && (s_present[i] > 0.f) && (s_present[jx] > 0.f);
        if (valid) { psum += pv; pnp += 1.f; }
    }
    #pragma unroll
    for (int off = 32; off; off >>= 1) {
        psum += __shfl_xor(psum, off);
        pnp  += __shfl_xor(pnp,  off);
    }
    if (lane == 0) { unsafeAtomicAdd(&s_red[1], psum); unsafeAtomicAdd(&s_red[2], pnp); }
    __syncthreads();
    if (t == 0) {
        float loss = s_red[0] + s_red[1] / fmaxf(s_red[2], 1.f);
        unsafeAtomicAdd(out, loss);
    }
}

extern "C" void kernel_launch(void* const* d_in, const int* in_sizes, int n_in,
                              void* d_out, int out_size, void* d_ws, size_t ws_size,
                              hipStream_t stream) {
    const float* emb   = (const float*)d_in[0];
    const int2* coords = (const int2*)d_in[1];
    const int*  y      = (const int*)d_in[2];
    float* out = (float*)d_out;
    float* ws  = (float*)d_ws;

    k_zero<<<(OFF_LAB + 255) / 256, 256, 0, stream>>>(ws, out);
    k_labels<<<(B_ * N_) / 256, 256, 0, stream>>>(coords, y, ws);
    k_accum<<<B_ * CHUNKS, BLK, 0, stream>>>(emb, ws);
    k_final_cent<<<(B_ * L_ * C_ + 255) / 256, 256, 0, stream>>>(ws);
    k_dist<<<B_ * CHUNKS, BLK, 0, stream>>>(emb, ws);
    k_final<<<B_, 256, 0, stream>>>(ws, out);
}

// Round 5
// 259.630 us; speedup vs baseline: 1.5844x; 1.5844x over previous
//
#include <hip/hip_runtime.h>

#define B_ 16
#define N_ 16384
#define C_ 128
#define H_ 512
#define W_ 512
#define L_ 65
#define FG 64

// ws layout (float units)
#define OFF_SUMS 0
#define OFF_CNT  (B_*L_*C_)              // 133120
#define OFF_DIST (OFF_CNT + B_*L_)       // 134160
#define OFF_LAB  (OFF_DIST + B_*L_)      // 135200 (ints from here, B_*N_)

#define APB 512   // points per k_accum block (32 blocks/image)
#define DPB 512   // points per k_dist block

__global__ __launch_bounds__(256) void k_zero(float* __restrict__ ws, float* __restrict__ out) {
    int i = blockIdx.x * 256 + threadIdx.x;
    if (i < OFF_LAB) ws[i] = 0.f;
    if (i == 0) out[0] = 0.f;
}

// one thread per point: gather label, save it; LDS-first count histogram
__global__ __launch_bounds__(256) void k_labels(const int2* __restrict__ coords,
                                                const int* __restrict__ y,
                                                float* __restrict__ ws) {
    __shared__ float s_cnt[L_];
    int t = blockIdx.x * 256 + threadIdx.x;           // 0 .. B*N-1 (block is within one image)
    int b = t >> 14;
    if (threadIdx.x < L_) s_cnt[threadIdx.x] = 0.f;
    __syncthreads();
    int2 rc = coords[t];
    int lab = y[(b << 18) + (rc.x << 9) + rc.y];
    ((int*)(ws + OFF_LAB))[t] = lab;
    atomicAdd(&s_cnt[lab], 1.f);
    __syncthreads();
    if (threadIdx.x < L_) {
        float c = s_cnt[threadIdx.x];
        if (c != 0.f) unsafeAtomicAdd(ws + OFF_CNT + b * L_ + threadIdx.x, c);
    }
}

// pass 1: segment-sum with NO atomics, NO shfl in the inner loop.
// wave w owns channels [32w,32w+32); half-wave h uses accumulator copy h.
__global__ __launch_bounds__(256) void k_accum(const float* __restrict__ emb,
                                               float* __restrict__ ws) {
    __shared__ float s_sum[2 * L_ * C_];   // two copies (half-wave parity)
    __shared__ int s_lab[APB];
    const int b = blockIdx.x >> 5;          // 32 blocks per image
    const int base = (blockIdx.x & 31) * APB;
    const int wave = threadIdx.x >> 6;      // 0..3 -> channel quarter
    const int lane = threadIdx.x & 63;
    const int half = lane >> 5, j = lane & 31;
    const int ch = 32 * wave + j;

    for (int i = threadIdx.x; i < 2 * L_ * C_; i += 256) s_sum[i] = 0.f;
    const int* labg = (const int*)(ws + OFF_LAB) + b * N_ + base;
    for (int i = threadIdx.x; i < APB; i += 256) s_lab[i] = labg[i];
    __syncthreads();

    const float* embp = emb + (size_t)b * N_ * C_ + (size_t)base * C_ + ch;
    float* copy = s_sum + half * (L_ * C_);

    for (int s0 = 0; s0 < APB / 2; s0 += 8) {
        float e[8]; int lb[8];
        #pragma unroll
        for (int u = 0; u < 8; ++u) {
            int p = 2 * (s0 + u) + half;    // 1 point per half-wave step
            e[u]  = embp[(size_t)p * C_];   // two 128B segments per wave-op
            lb[u] = s_lab[p];               // LDS broadcast read
        }
        #pragma unroll
        for (int u = 0; u < 8; ++u) {
            copy[lb[u] * C_ + ch] += e[u];  // plain RMW: (wave,half) exclusive cell
        }
    }
    __syncthreads();
    float* gs = ws + OFF_SUMS + b * L_ * C_;
    for (int i = threadIdx.x; i < L_ * C_; i += 256)
        unsafeAtomicAdd(&gs[i], s_sum[i] + s_sum[L_ * C_ + i]);
}

__global__ __launch_bounds__(256) void k_final_cent(float* __restrict__ ws) {
    int i = blockIdx.x * 256 + threadIdx.x;
    if (i >= B_ * L_ * C_) return;
    float cnt = ws[OFF_CNT + (i / C_)];
    ws[OFF_SUMS + i] = ws[OFF_SUMS + i] / fmaxf(cnt, 1.f);
}

// pass 2: point-per-lane, full 128-ch reduction in registers (no cross-lane ops)
__global__ __launch_bounds__(256) void k_dist(const float* __restrict__ emb,
                                              float* __restrict__ ws) {
    __shared__ __align__(16) float4 s_cent4[L_ * 33];  // row stride 33 float4 (132 floats)
    __shared__ float s_dist[L_];
    const int b = blockIdx.x >> 5;
    const int base = (blockIdx.x & 31) * DPB;

    const float* gcent = ws + OFF_SUMS + b * L_ * C_;
    for (int i = threadIdx.x; i < L_ * 32; i += 256) {
        int l = i >> 5, q = i & 31;
        s_cent4[l * 33 + q] = ((const float4*)gcent)[l * 32 + q];
    }
    if (threadIdx.x < L_) s_dist[threadIdx.x] = 0.f;
    __syncthreads();

    const int* labg = (const int*)(ws + OFF_LAB) + b * N_ + base;
    const float4* embp = (const float4*)(emb + (size_t)b * N_ * C_ + (size_t)base * C_);

    for (int it = 0; it < DPB; it += 256) {
        int p = it + threadIdx.x;          // this lane's point
        int lb = labg[p];
        const float4* ep = embp + (size_t)p * 32;
        const float4* cp = s_cent4 + lb * 33;
        float acc = 0.f;
        #pragma unroll 8
        for (int q = 0; q < 32; ++q) {
            float4 e = ep[q], c = cp[q];
            float dx = e.x - c.x, dy = e.y - c.y;
            float dz = e.z - c.z, dw = e.w - c.w;
            acc += dx * dx + dy * dy + dz * dz + dw * dw;
        }
        atomicAdd(&s_dist[lb], sqrtf(fmaxf(acc, 1e-12f)));
    }
    __syncthreads();
    if (threadIdx.x < L_) {
        float d = s_dist[threadIdx.x];
        if (d != 0.f) unsafeAtomicAdd(ws + OFF_DIST + b * L_ + threadIdx.x, d);
    }
}

#define CSTRIDE 132  // 128 + 4 pad -> conflict-free float4 tile reads

__global__ __launch_bounds__(256) void k_final(float* __restrict__ ws, float* __restrict__ out) {
    __shared__ __align__(16) float s_cc[FG * CSTRIDE];
    __shared__ float s_present[FG];
    __shared__ float s_red[3];  // [0]=pull, [1]=push num, [2]=npairs
    const int b = blockIdx.x;
    const int t = threadIdx.x;

    const float* gcent = ws + OFF_SUMS + b * L_ * C_;
    for (int i = t; i < FG * C_; i += 256) {
        int l = i >> 7, ch = i & 127;
        s_cc[l * CSTRIDE + ch] = gcent[(l + 1) * C_ + ch];
    }
    if (t < 3) s_red[t] = 0.f;
    if (t < FG) {  // exactly wave 0
        float cnt = ws[OFF_CNT + b * L_ + 1 + t];
        s_present[t] = (cnt > 0.f) ? 1.f : 0.f;
        float pl = (cnt > 0.f) ? ws[OFF_DIST + b * L_ + 1 + t] / cnt : 0.f;
        #pragma unroll
        for (int off = 32; off; off >>= 1) pl += __shfl_xor(pl, off);
        if (t == 0) s_red[0] = pl;
    }
    __syncthreads();

    const int wave = t >> 6, lane = t & 63;
    const int ti = lane >> 3, tj = lane & 7;
    float psum = 0.f, pnp = 0.f;
    for (int tt = wave; tt < 36; tt += 4) {
        int a = 0, c = tt;
        while (c >= 8 - a) { c -= 8 - a; ++a; }
        c += a;  // tile (a, c), a <= c
        int i = a * 8 + ti, jx = c * 8 + tj;
        float acc = 0.f;
        #pragma unroll
        for (int ch = 0; ch < C_; ch += 4) {
            float4 xi = *(const float4*)&s_cc[i * CSTRIDE + ch];
            float4 xj = *(const float4*)&s_cc[jx * CSTRIDE + ch];
            float dx = xi.x - xj.x, dy = xi.y - xj.y;
            float dz = xi.z - xj.z, dw = xi.w - xj.w;
            acc += dx * dx + dy * dy + dz * dz + dw * dw;
        }
        float dm = sqrtf(fmaxf(acc, 1e-12f));
        float pv = fmaxf(1.f - dm, 0.f);           // PUSH_MARGIN = 1
        bool valid = (i < jx) && (s_present[i] > 0.f) && (s_present[jx] > 0.f);
        if (valid) { psum += pv; pnp += 1.f; }
    }
    #pragma unroll
    for (int off = 32; off; off >>= 1) {
        psum += __shfl_xor(psum, off);
        pnp  += __shfl_xor(pnp,  off);
    }
    if (lane == 0) { unsafeAtomicAdd(&s_red[1], psum); unsafeAtomicAdd(&s_red[2], pnp); }
    __syncthreads();
    if (t == 0) {
        float loss = s_red[0] + s_red[1] / fmaxf(s_red[2], 1.f);
        unsafeAtomicAdd(out, loss);
    }
}

extern "C" void kernel_launch(void* const* d_in, const int* in_sizes, int n_in,
                              void* d_out, int out_size, void* d_ws, size_t ws_size,
                              hipStream_t stream) {
    const float* emb   = (const float*)d_in[0];
    const int2* coords = (const int2*)d_in[1];
    const int*  y      = (const int*)d_in[2];
    float* out = (float*)d_out;
    float* ws  = (float*)d_ws;

    k_zero<<<(OFF_LAB + 255) / 256, 256, 0, stream>>>(ws, out);
    k_labels<<<(B_ * N_) / 256, 256, 0, stream>>>(coords, y, ws);
    k_accum<<<B_ * (N_ / APB), 256, 0, stream>>>(emb, ws);
    k_final_cent<<<(B_ * L_ * C_ + 255) / 256, 256, 0, stream>>>(ws);
    k_dist<<<B_ * (N_ / DPB), 256, 0, stream>>>(emb, ws);
    k_final<<<B_, 256, 0, stream>>>(ws, out);
}